// Round 1
// baseline (194.574 us; speedup 1.0000x reference)
//
#include <hip/hip_runtime.h>
#include <hip/hip_cooperative_groups.h>

#define CC 64
#define LL 1024
#define LOG2E 1.44269504f

typedef unsigned short u16;
typedef unsigned int u32;
typedef __attribute__((ext_vector_type(8))) short short8;
typedef __attribute__((ext_vector_type(4))) float floatx4;

// RN ties-away float->bf16 (2 VALU ops)
static __device__ __forceinline__ u16 f2b(float f) {
  return (u16)((__float_as_uint(f) + 0x8000u) >> 16);
}
static __device__ __forceinline__ u32 pk2(float a, float b) {
  return ((__float_as_uint(a) + 0x8000u) >> 16) |
         ((__float_as_uint(b) + 0x8000u) & 0xffff0000u);
}
// 1-op truncating pack: low16 <- hi16(a), high16 <- hi16(b)  (v_perm_b32)
static __device__ __forceinline__ u32 pk2t(float a, float b) {
  return __builtin_amdgcn_perm(__float_as_uint(b), __float_as_uint(a), 0x07060302u);
}
static __device__ __forceinline__ short8 mk8(u32 a, u32 b, u32 c, u32 d) {
  union { u32 u[4]; short8 s; } t;
  t.u[0] = a; t.u[1] = b; t.u[2] = c; t.u[3] = d;
  return t.s;
}

// ---- LDS union layout (u16 indices) for the QKV phase -----------------------
// whi_s : [0, 13824)     3 x [64 o][72] bf16 W, row stride 72 (bank-conflict pad)
// xh_s  : [13824, 23040) 2 x [64 l][72] x-tile bf16
// tbuf  : [23040, 27648) 4 x [16][72] per-wave transpose buf
// b_s   : [27648, 28032) 192 floats
// total 56,064 B -> 2 blocks/CU (= exactly the 512-block cooperative grid)
#define LDS_U16 28032

// ---------------- QKV phase: W->bf16 in LDS, projection, transposes ----------
static __device__ __forceinline__ void qkv_body(
    const float* __restrict__ x,
    const float* __restrict__ Wq, const float* __restrict__ bq,
    const float* __restrict__ Wk, const float* __restrict__ bk,
    const float* __restrict__ Wv, const float* __restrict__ bv,
    u16* __restrict__ qT, u16* __restrict__ kT, u16* __restrict__ vO,
    u16* smem_u)
{
  u16* const whi_s  = smem_u;
  u16* const xh_s   = smem_u + 13824;
  u16* const tbuf_s = smem_u + 23040;
  float* const b_s  = (float*)(smem_u + 27648);

  const int tid  = threadIdx.x;
  const int wave = tid >> 6;
  const int lane = tid & 63;
  const int l16  = lane & 15;
  const int quad = lane >> 4;

  const int bt = blockIdx.x & 63;                  // XCD pin matches attn consumer
  const int l0 = (blockIdx.x >> 6) << 7;           // 128 l's per block

  const int lx = tid & 63;
  const int cg = (tid >> 6) << 4;
  const float* xp = x + ((size_t)bt * CC + cg) * LL + l0 + lx;

  // issue chunk-0 x loads first: HBM latency hides under the W-convert loop
  float v0[16];
  #pragma unroll
  for (int e = 0; e < 16; ++e) v0[e] = xp[(size_t)e * LL];

  // one-time (per block) W -> bf16 into padded LDS, log2e folded into Wq
  #pragma unroll
  for (int rep = 0; rep < 24; ++rep) {
    const int i = (rep * 256 + tid) * 2;           // 0..12286, even
    const int m = i >> 12;                         // uniform per rep
    const int r = (i >> 6) & 63;
    const int c = i & 63;
    const int j = i & 4095;
    const float* W = (m == 0) ? Wq : (m == 1) ? Wk : Wv;
    const float sc = (m == 0) ? LOG2E : 1.0f;
    *(u32*)(whi_s + m * 4608 + r * 72 + c) = pk2(W[j] * sc, W[j + 1] * sc);
  }
  if (tid < 192)
    b_s[tid] = (tid < 64) ? bq[tid] * LOG2E
             : (tid < 128) ? bk[tid - 64] : bv[tid - 128];

  #pragma unroll
  for (int e = 0; e < 16; e += 2)
    *(u32*)(xh_s + lx * 72 + cg + e) = pk2(v0[e], v0[e + 1]);
  __syncthreads();

  // prefetch chunk 1 into registers (drains during chunk-0 compute)
  float v1[16];
  #pragma unroll
  for (int e = 0; e < 16; ++e) v1[e] = xp[64 + (size_t)e * LL];

  u16* tb = tbuf_s + wave * 1152;

  auto compute = [&](int ch) {
    const int lc0 = l0 + (ch << 6);
    const u16* xr_h = xh_s + ch * 4608 + (wave * 16 + l16) * 72 + quad * 8;
    const short8 xh0 = *(const short8*)(xr_h);
    const short8 xh1 = *(const short8*)(xr_h + 32);

    #pragma unroll
    for (int ot = 0; ot < 12; ++ot) {
      const int m = ot >> 2;
      const int off = m * 4608 + ((ot & 3) * 16 + l16) * 72 + quad * 8;
      const short8 ah0 = *(const short8*)(whi_s + off);
      const short8 ah1 = *(const short8*)(whi_s + off + 32);

      floatx4 acc = (floatx4){0.f, 0.f, 0.f, 0.f};
      acc = __builtin_amdgcn_mfma_f32_16x16x32_bf16(ah0, xh0, acc, 0, 0, 0);
      acc = __builtin_amdgcn_mfma_f32_16x16x32_bf16(ah1, xh1, acc, 0, 0, 0);

      float ov[4];
      #pragma unroll
      for (int r = 0; r < 4; ++r)
        ov[r] = acc[r] + b_s[ot * 16 + quad * 4 + r];

      if (ot < 8) {
        // D lane holds (o = quad*4+r, l = l16); write transposed [l][o]
        uint2 pv;
        pv.x = pk2(ov[0], ov[1]);
        pv.y = pk2(ov[2], ov[3]);
        *(uint2*)(tb + l16 * 72 + (ot & 3) * 16 + quad * 4) = pv;
        if ((ot & 3) == 3) {
          asm volatile("" ::: "memory");
          u16* gdst = ((ot < 4) ? qT : kT) + ((size_t)(bt * LL + lc0 + wave * 16)) * CC;
          const int rr = lane >> 3;
          const int c8 = (lane & 7) * 8;
          #pragma unroll
          for (int s2 = 0; s2 < 2; ++s2) {
            const int row = s2 * 8 + rr;
            uint4 val = *(const uint4*)(tb + row * 72 + c8);
            *(uint4*)(gdst + row * CC + c8) = val;   // 128B-contiguous rows
          }
          asm volatile("" ::: "memory");
        }
      } else {
        const int ob = (ot - 8) * 16 + quad * 4;
        u16* vdst = vO + ((size_t)(bt * CC + ob)) * LL + lc0 + wave * 16 + l16;
        #pragma unroll
        for (int r = 0; r < 4; ++r)
          vdst[(size_t)r * LL] = f2b(ov[r]);
      }
    }
  };

  compute(0);

  #pragma unroll
  for (int e = 0; e < 16; e += 2)
    *(u32*)(xh_s + 4608 + lx * 72 + cg + e) = pk2(v1[e], v1[e + 1]);
  __syncthreads();

  compute(1);
}

// ---------------- Attention phase: flash, no-max softmax ---------------------
// grid 512 = 64 bt (XCD-pinned) x 8 chunks of 128 i; 4 waves x 32 i each.
// Double-buffered K/V, ONE barrier/iter. K-row permutation trick (see prev rev).
static __device__ __forceinline__ void attn_body(
    const u16* __restrict__ qT, const u16* __restrict__ kT,
    const u16* __restrict__ vB, float* __restrict__ out,
    u16* smem)
{
  const int tid  = threadIdx.x;
  const int wave = tid >> 6;
  const int lane = tid & 63;
  const int l16  = lane & 15;
  const int quad = lane >> 4;

  const int bt    = blockIdx.x & 63;          // XCD pin: blockIdx%8 == bt%8
  const int chunk = blockIdx.x >> 6;          // 0..7
  const int i0w   = (chunk << 7) + (wave << 5);

  const u16* kbase = kT + (size_t)bt * LL * CC;
  const u16* vbase = vB + (size_t)bt * CC * LL;

  short8 qf[2][2];
  {
    const u16* qb = qT + (size_t)bt * LL * CC;
    #pragma unroll
    for (int s = 0; s < 2; ++s) {
      const u16* qr = qb + (size_t)(i0w + s * 16 + l16) * CC + quad * 8;
      qf[s][0] = *(const short8*)(qr);
      qf[s][1] = *(const short8*)(qr + 32);
    }
  }

  floatx4 O[2][4];
  #pragma unroll
  for (int s = 0; s < 2; ++s)
    #pragma unroll
    for (int cf = 0; cf < 4; ++cf)
      O[s][cf] = (floatx4){0.f, 0.f, 0.f, 0.f};
  float lsA[2] = {0.f, 0.f}, lsB[2] = {0.f, 0.f};

  const int r_st = tid >> 2;            // global j row this thread stages
  const int c_st = (tid & 3) << 4;
  // sigma(j): j = kt*32 + q*8 + b*4 + r  ->  row = kt*32 + b*16 + q*4 + r
  const int sr = (r_st & 0x20) | ((r_st & 4) << 2) | ((r_st & 0x18) >> 1) | (r_st & 3);

  // prologue: tile 0 -> buf0 (K rows permuted, V rows true)
  {
    uint4 k0 = *(const uint4*)(kbase + (size_t)r_st * CC + c_st);
    uint4 k1 = *(const uint4*)(kbase + (size_t)r_st * CC + c_st + 8);
    uint4 v0 = *(const uint4*)(vbase + (size_t)r_st * LL + c_st);
    uint4 v1 = *(const uint4*)(vbase + (size_t)r_st * LL + c_st + 8);
    *(uint4*)(smem + sr * 72 + c_st)              = k0;
    *(uint4*)(smem + sr * 72 + c_st + 8)          = k1;
    *(uint4*)(smem + 4608 + r_st * 72 + c_st)     = v0;
    *(uint4*)(smem + 4608 + r_st * 72 + c_st + 8) = v1;
  }
  __syncthreads();

  for (int it = 0; it < 16; ++it) {
    u16* ktc = smem + (it & 1) * 9216;
    u16* vtc = ktc + 4608;

    uint4 rk0, rk1, rv0, rv1;
    if (it < 15) {
      const int jb = (it + 1) << 6;
      rk0 = *(const uint4*)(kbase + (size_t)(jb + r_st) * CC + c_st);
      rk1 = *(const uint4*)(kbase + (size_t)(jb + r_st) * CC + c_st + 8);
      rv0 = *(const uint4*)(vbase + (size_t)r_st * LL + jb + c_st);
      rv1 = *(const uint4*)(vbase + (size_t)r_st * LL + jb + c_st + 8);
    }

    // S^T: D[j_perm][i] = sum_c K[j][c] * Q[i][c]  (i = lane&15)
    floatx4 S[2][4];
    __builtin_amdgcn_s_setprio(1);
    #pragma unroll
    for (int jt = 0; jt < 4; ++jt) {
      const u16* ka = ktc + (jt * 16 + l16) * 72 + quad * 8;
      const short8 a0 = *(const short8*)(ka);
      const short8 a1 = *(const short8*)(ka + 32);
      #pragma unroll
      for (int s = 0; s < 2; ++s) {
        floatx4 acc = (floatx4){0.f, 0.f, 0.f, 0.f};
        acc = __builtin_amdgcn_mfma_f32_16x16x32_bf16(a0, qf[s][0], acc, 0, 0, 0);
        acc = __builtin_amdgcn_mfma_f32_16x16x32_bf16(a1, qf[s][1], acc, 0, 0, 0);
        S[s][jt] = acc;
      }
    }
    __builtin_amdgcn_s_setprio(0);

    // V fragments issued EARLY: lgkm latency hides under the exp2 block
    short8 v0f[4], v1f[4];
    #pragma unroll
    for (int cf = 0; cf < 4; ++cf) {
      const u16* va = vtc + (cf * 16 + l16) * 72 + quad * 8;
      v0f[cf] = *(const short8*)(va);
      v1f[cf] = *(const short8*)(va + 32);
    }

    // exp2 + partial sums + in-register pack (P stays in VGPRs)
    uint2 pp[2][4];
    #pragma unroll
    for (int s = 0; s < 2; ++s)
      #pragma unroll
      for (int jt = 0; jt < 4; ++jt) {
        const float e0 = __builtin_amdgcn_exp2f(S[s][jt][0]);
        const float e1 = __builtin_amdgcn_exp2f(S[s][jt][1]);
        const float e2 = __builtin_amdgcn_exp2f(S[s][jt][2]);
        const float e3 = __builtin_amdgcn_exp2f(S[s][jt][3]);
        lsA[s] += e0 + e1;
        lsB[s] += e2 + e3;
        pp[s][jt].x = pk2t(e0, e1);
        pp[s][jt].y = pk2t(e2, e3);
      }

    // O += P * V : A = P (in regs, j-order restored by sigma), B = v[c][j]
    __builtin_amdgcn_s_setprio(1);
    #pragma unroll
    for (int s = 0; s < 2; ++s) {
      const short8 pa0 = mk8(pp[s][0].x, pp[s][0].y, pp[s][1].x, pp[s][1].y);
      const short8 pa1 = mk8(pp[s][2].x, pp[s][2].y, pp[s][3].x, pp[s][3].y);
      #pragma unroll
      for (int cf = 0; cf < 4; ++cf) {
        O[s][cf] = __builtin_amdgcn_mfma_f32_16x16x32_bf16(pa0, v0f[cf], O[s][cf], 0, 0, 0);
        O[s][cf] = __builtin_amdgcn_mfma_f32_16x16x32_bf16(pa1, v1f[cf], O[s][cf], 0, 0, 0);
      }
    }
    __builtin_amdgcn_s_setprio(0);

    if (it < 15) {
      u16* ktn = smem + ((it + 1) & 1) * 9216;
      *(uint4*)(ktn + sr * 72 + c_st)              = rk0;
      *(uint4*)(ktn + sr * 72 + c_st + 8)          = rk1;
      *(uint4*)(ktn + 4608 + r_st * 72 + c_st)     = rv0;
      *(uint4*)(ktn + 4608 + r_st * 72 + c_st + 8) = rv1;
    }
    __syncthreads();
  }

  float lsum[2];
  #pragma unroll
  for (int s = 0; s < 2; ++s) {
    lsum[s] = lsA[s] + lsB[s];
    lsum[s] += __shfl_xor(lsum[s], 16, 64);
    lsum[s] += __shfl_xor(lsum[s], 32, 64);
  }

  __syncthreads();   // reuse LDS for epilogue transpose
  float* of = (float*)smem + wave * 1280;   // [64 c][20] per wave
  #pragma unroll
  for (int s = 0; s < 2; ++s) {
    #pragma unroll
    for (int r = 0; r < 4; ++r) {
      const float rl = __builtin_amdgcn_rcpf(__shfl(lsum[s], quad * 4 + r, 64));
      #pragma unroll
      for (int cf = 0; cf < 4; ++cf)
        O[s][cf][r] *= rl;
    }
    asm volatile("" ::: "memory");
    #pragma unroll
    for (int cf = 0; cf < 4; ++cf)
      #pragma unroll
      for (int r = 0; r < 4; ++r)
        of[(cf * 16 + l16) * 20 + quad * 4 + r] = O[s][cf][r];
    asm volatile("" ::: "memory");
    float* ob = out + ((size_t)bt * CC) * LL + i0w + s * 16;
    #pragma unroll
    for (int rr = 0; rr < 4; ++rr) {
      const int c = rr * 16 + l16;
      float4 val = *(const float4*)(of + c * 20 + quad * 4);
      *(float4*)(ob + (size_t)c * LL + quad * 4) = val;
    }
    asm volatile("" ::: "memory");
  }
}

// ---------------- kernels ----------------------------------------------------
__global__ __launch_bounds__(256) void qkv_kernel(
    const float* __restrict__ x,
    const float* __restrict__ Wq, const float* __restrict__ bq,
    const float* __restrict__ Wk, const float* __restrict__ bk,
    const float* __restrict__ Wv, const float* __restrict__ bv,
    u16* __restrict__ qT, u16* __restrict__ kT, u16* __restrict__ vO)
{
  __shared__ __align__(16) u16 s[LDS_U16];
  qkv_body(x, Wq, bq, Wk, bk, Wv, bv, qT, kT, vO, s);
}

__global__ __launch_bounds__(256) void attn_kernel(
    const u16* __restrict__ qT, const u16* __restrict__ kT,
    const u16* __restrict__ vB, float* __restrict__ out)
{
  __shared__ __align__(16) u16 s[18432];
  attn_body(qT, kT, vB, out, s);
}

// single cooperative kernel: qkv -> grid sync -> attn (intermediates stay in
// the bt-pinned XCD L2 across the sync; removes 2 launch gaps + w_prep)
__global__ __launch_bounds__(256, 2) void fused_kernel(
    const float* __restrict__ x,
    const float* __restrict__ Wq, const float* __restrict__ bq,
    const float* __restrict__ Wk, const float* __restrict__ bk,
    const float* __restrict__ Wv, const float* __restrict__ bv,
    u16* __restrict__ qT, u16* __restrict__ kT, u16* __restrict__ vO,
    float* __restrict__ out)
{
  __shared__ __align__(16) u16 s[LDS_U16];
  qkv_body(x, Wq, bq, Wk, bk, Wv, bv, qT, kT, vO, s);
  cooperative_groups::this_grid().sync();
  attn_body(qT, kT, vO, out, s);
}

extern "C" void kernel_launch(void* const* d_in, const int* in_sizes, int n_in,
                              void* d_out, int out_size, void* d_ws, size_t ws_size,
                              hipStream_t stream) {
  const float* x  = (const float*)d_in[0];
  const float* Wq = (const float*)d_in[1];
  const float* bq = (const float*)d_in[2];
  const float* Wk = (const float*)d_in[3];
  const float* bk = (const float*)d_in[4];
  const float* Wv = (const float*)d_in[5];
  const float* bv = (const float*)d_in[6];
  float* out = (float*)d_out;

  u16* qTp = (u16*)d_ws;                          // 8 MB
  u16* kTp = qTp + (size_t)64 * LL * CC;          // 8 MB
  u16* vp  = kTp + (size_t)64 * LL * CC;          // 8 MB

  void* args[] = {(void*)&x, (void*)&Wq, (void*)&bq, (void*)&Wk, (void*)&bk,
                  (void*)&Wv, (void*)&bv, (void*)&qTp, (void*)&kTp, (void*)&vp,
                  (void*)&out};
  hipError_t e = hipLaunchCooperativeKernel((const void*)fused_kernel,
                                            dim3(512), dim3(256), args, 0, stream);
  if (e != hipSuccess) {
    // fallback: 2-kernel path (w_prep folded into qkv either way)
    qkv_kernel<<<512, 256, 0, stream>>>(x, Wq, bq, Wk, bk, Wv, bv, qTp, kTp, vp);
    attn_kernel<<<512, 256, 0, stream>>>(qTp, kTp, vp, out);
  }
}

// Round 2
// 114.641 us; speedup vs baseline: 1.6972x; 1.6972x over previous
//
#include <hip/hip_runtime.h>

#define CC 64
#define LL 1024
#define LOG2E 1.44269504f

typedef unsigned short u16;
typedef unsigned int u32;
typedef __attribute__((ext_vector_type(8))) short short8;
typedef __attribute__((ext_vector_type(4))) float floatx4;

// RN ties-away float->bf16 (2 VALU ops)
static __device__ __forceinline__ u16 f2b(float f) {
  return (u16)((__float_as_uint(f) + 0x8000u) >> 16);
}
static __device__ __forceinline__ u32 pk2(float a, float b) {
  return ((__float_as_uint(a) + 0x8000u) >> 16) |
         ((__float_as_uint(b) + 0x8000u) & 0xffff0000u);
}
// 1-op truncating pack: low16 <- hi16(a), high16 <- hi16(b)  (v_perm_b32)
static __device__ __forceinline__ u32 pk2t(float a, float b) {
  return __builtin_amdgcn_perm(__float_as_uint(b), __float_as_uint(a), 0x07060302u);
}
static __device__ __forceinline__ short8 mk8(u32 a, u32 b, u32 c, u32 d) {
  union { u32 u[4]; short8 s; } t;
  t.u[0] = a; t.u[1] = b; t.u[2] = c; t.u[3] = d;
  return t.s;
}

// ---- LDS layout (u16 indices) for the QKV kernel ----------------------------
// whi_s : [0, 13824)     3 x [64 o][72] bf16 W, row stride 72 (bank-conflict pad)
// xh_s  : [13824, 23040) 2 x [64 l][72] x-tile bf16
// tbuf  : [23040, 27648) 4 x [16][72] per-wave transpose buf
// b_s   : [27648, 28032) 192 floats
#define LDS_U16 28032

// ---------------- QKV kernel: W->bf16 in LDS, projection, transposes ---------
// grid 512 = 64 bt x 8 l-blocks of 128; 2 l-chunks of 64 pipelined.
__global__ __launch_bounds__(256) void qkv_kernel(
    const float* __restrict__ x,
    const float* __restrict__ Wq, const float* __restrict__ bq,
    const float* __restrict__ Wk, const float* __restrict__ bk,
    const float* __restrict__ Wv, const float* __restrict__ bv,
    u16* __restrict__ qT, u16* __restrict__ kT, u16* __restrict__ vO)
{
  __shared__ __align__(16) u16 smem_u[LDS_U16];
  u16* const whi_s  = smem_u;
  u16* const xh_s   = smem_u + 13824;
  u16* const tbuf_s = smem_u + 23040;
  float* const b_s  = (float*)(smem_u + 27648);

  const int tid  = threadIdx.x;
  const int wave = tid >> 6;
  const int lane = tid & 63;
  const int l16  = lane & 15;
  const int quad = lane >> 4;

  const int bt = blockIdx.x & 63;                  // XCD pin matches attn consumer
  const int l0 = (blockIdx.x >> 6) << 7;           // 128 l's per block

  const int lx = tid & 63;
  const int cg = (tid >> 6) << 4;
  const float* xp = x + ((size_t)bt * CC + cg) * LL + l0 + lx;

  // issue chunk-0 x loads first: HBM latency hides under the W-convert loop
  float v0[16];
  #pragma unroll
  for (int e = 0; e < 16; ++e) v0[e] = xp[(size_t)e * LL];

  // one-time (per block) W -> bf16 into padded LDS, log2e folded into Wq
  #pragma unroll
  for (int rep = 0; rep < 24; ++rep) {
    const int i = (rep * 256 + tid) * 2;           // 0..12286, even
    const int m = i >> 12;                         // uniform per rep
    const int r = (i >> 6) & 63;
    const int c = i & 63;
    const int j = i & 4095;
    const float* W = (m == 0) ? Wq : (m == 1) ? Wk : Wv;
    const float sc = (m == 0) ? LOG2E : 1.0f;
    *(u32*)(whi_s + m * 4608 + r * 72 + c) = pk2(W[j] * sc, W[j + 1] * sc);
  }
  if (tid < 192)
    b_s[tid] = (tid < 64) ? bq[tid] * LOG2E
             : (tid < 128) ? bk[tid - 64] : bv[tid - 128];

  #pragma unroll
  for (int e = 0; e < 16; e += 2)
    *(u32*)(xh_s + lx * 72 + cg + e) = pk2(v0[e], v0[e + 1]);
  __syncthreads();

  // prefetch chunk 1 into registers (drains during chunk-0 compute)
  float v1[16];
  #pragma unroll
  for (int e = 0; e < 16; ++e) v1[e] = xp[64 + (size_t)e * LL];

  u16* tb = tbuf_s + wave * 1152;

  auto compute = [&](int ch) {
    const int lc0 = l0 + (ch << 6);
    const u16* xr_h = xh_s + ch * 4608 + (wave * 16 + l16) * 72 + quad * 8;
    const short8 xh0 = *(const short8*)(xr_h);
    const short8 xh1 = *(const short8*)(xr_h + 32);

    #pragma unroll
    for (int ot = 0; ot < 12; ++ot) {
      const int m = ot >> 2;
      const int off = m * 4608 + ((ot & 3) * 16 + l16) * 72 + quad * 8;
      const short8 ah0 = *(const short8*)(whi_s + off);
      const short8 ah1 = *(const short8*)(whi_s + off + 32);

      floatx4 acc = (floatx4){0.f, 0.f, 0.f, 0.f};
      acc = __builtin_amdgcn_mfma_f32_16x16x32_bf16(ah0, xh0, acc, 0, 0, 0);
      acc = __builtin_amdgcn_mfma_f32_16x16x32_bf16(ah1, xh1, acc, 0, 0, 0);

      float ov[4];
      #pragma unroll
      for (int r = 0; r < 4; ++r)
        ov[r] = acc[r] + b_s[ot * 16 + quad * 4 + r];

      if (ot < 8) {
        // D lane holds (o = quad*4+r, l = l16); write transposed [l][o]
        uint2 pv;
        pv.x = pk2(ov[0], ov[1]);
        pv.y = pk2(ov[2], ov[3]);
        *(uint2*)(tb + l16 * 72 + (ot & 3) * 16 + quad * 4) = pv;
        if ((ot & 3) == 3) {
          asm volatile("" ::: "memory");
          u16* gdst = ((ot < 4) ? qT : kT) + ((size_t)(bt * LL + lc0 + wave * 16)) * CC;
          const int rr = lane >> 3;
          const int c8 = (lane & 7) * 8;
          #pragma unroll
          for (int s2 = 0; s2 < 2; ++s2) {
            const int row = s2 * 8 + rr;
            uint4 val = *(const uint4*)(tb + row * 72 + c8);
            *(uint4*)(gdst + row * CC + c8) = val;   // 128B-contiguous rows
          }
          asm volatile("" ::: "memory");
        }
      } else {
        const int ob = (ot - 8) * 16 + quad * 4;
        u16* vdst = vO + ((size_t)(bt * CC + ob)) * LL + lc0 + wave * 16 + l16;
        #pragma unroll
        for (int r = 0; r < 4; ++r)
          vdst[(size_t)r * LL] = f2b(ov[r]);
      }
    }
  };

  compute(0);

  #pragma unroll
  for (int e = 0; e < 16; e += 2)
    *(u32*)(xh_s + 4608 + lx * 72 + cg + e) = pk2(v1[e], v1[e + 1]);
  __syncthreads();

  compute(1);
}

// ---------------- Attention kernel: flash, no-max softmax --------------------
// grid 1024 = 64 bt (XCD-pinned) x 16 chunks of 64 i; 4 waves x 16 i each.
// LDS 36,864 B -> 4 blocks/CU resident (16 waves/CU, ~45% occupancy): the
// round-1 counters showed 21% occupancy + 7% MfmaUtil = latency-bound, so
// this trades per-wave K-fragment reuse for 2x latency hiding.
// Double-buffered K/V, ONE barrier/iter. K-row permutation trick: K tile rows
// stored permuted in LDS (j = 32kt+8q+4b+r -> row 32kt+16b+4q+r) so S^T
// output regs across the tile-pair are exactly the K=32 A-fragment for PV.
__global__ __launch_bounds__(256) void attn_kernel(
    const u16* __restrict__ qT, const u16* __restrict__ kT,
    const u16* __restrict__ vB, float* __restrict__ out)
{
  __shared__ __align__(16) u16 smem[18432];   // 36,864 B: kt0|vt0|kt1|vt1
  const int tid  = threadIdx.x;
  const int wave = tid >> 6;
  const int lane = tid & 63;
  const int l16  = lane & 15;
  const int quad = lane >> 4;

  const int bt    = blockIdx.x & 63;          // XCD pin: blockIdx%8 == bt%8
  const int chunk = blockIdx.x >> 6;          // 0..15
  const int i0w   = (chunk << 6) + (wave << 4);   // 16 i rows per wave

  const u16* kbase = kT + (size_t)bt * LL * CC;
  const u16* vbase = vB + (size_t)bt * CC * LL;

  short8 qf[2];
  {
    const u16* qr = qT + (size_t)bt * LL * CC + (size_t)(i0w + l16) * CC + quad * 8;
    qf[0] = *(const short8*)(qr);
    qf[1] = *(const short8*)(qr + 32);
  }

  floatx4 O[4];
  #pragma unroll
  for (int cf = 0; cf < 4; ++cf)
    O[cf] = (floatx4){0.f, 0.f, 0.f, 0.f};
  float lsA = 0.f, lsB = 0.f;

  const int r_st = tid >> 2;            // global j row this thread stages
  const int c_st = (tid & 3) << 4;
  // sigma(j): j = kt*32 + q*8 + b*4 + r  ->  row = kt*32 + b*16 + q*4 + r
  const int sr = (r_st & 0x20) | ((r_st & 4) << 2) | ((r_st & 0x18) >> 1) | (r_st & 3);

  // prologue: tile 0 -> buf0 (K rows permuted, V rows true)
  {
    uint4 k0 = *(const uint4*)(kbase + (size_t)r_st * CC + c_st);
    uint4 k1 = *(const uint4*)(kbase + (size_t)r_st * CC + c_st + 8);
    uint4 v0 = *(const uint4*)(vbase + (size_t)r_st * LL + c_st);
    uint4 v1 = *(const uint4*)(vbase + (size_t)r_st * LL + c_st + 8);
    *(uint4*)(smem + sr * 72 + c_st)              = k0;
    *(uint4*)(smem + sr * 72 + c_st + 8)          = k1;
    *(uint4*)(smem + 4608 + r_st * 72 + c_st)     = v0;
    *(uint4*)(smem + 4608 + r_st * 72 + c_st + 8) = v1;
  }
  __syncthreads();

  for (int it = 0; it < 16; ++it) {
    u16* ktc = smem + (it & 1) * 9216;
    u16* vtc = ktc + 4608;

    uint4 rk0, rk1, rv0, rv1;
    if (it < 15) {
      const int jb = (it + 1) << 6;
      rk0 = *(const uint4*)(kbase + (size_t)(jb + r_st) * CC + c_st);
      rk1 = *(const uint4*)(kbase + (size_t)(jb + r_st) * CC + c_st + 8);
      rv0 = *(const uint4*)(vbase + (size_t)r_st * LL + jb + c_st);
      rv1 = *(const uint4*)(vbase + (size_t)r_st * LL + jb + c_st + 8);
    }

    // S^T: D[j_perm][i] = sum_c K[j][c] * Q[i][c]  (i = lane&15)
    floatx4 S[4];
    __builtin_amdgcn_s_setprio(1);
    #pragma unroll
    for (int jt = 0; jt < 4; ++jt) {
      const u16* ka = ktc + (jt * 16 + l16) * 72 + quad * 8;
      const short8 a0 = *(const short8*)(ka);
      const short8 a1 = *(const short8*)(ka + 32);
      floatx4 acc = (floatx4){0.f, 0.f, 0.f, 0.f};
      acc = __builtin_amdgcn_mfma_f32_16x16x32_bf16(a0, qf[0], acc, 0, 0, 0);
      acc = __builtin_amdgcn_mfma_f32_16x16x32_bf16(a1, qf[1], acc, 0, 0, 0);
      S[jt] = acc;
    }
    __builtin_amdgcn_s_setprio(0);

    // V fragments issued EARLY: lgkm latency hides under the exp2 block
    short8 v0f[4], v1f[4];
    #pragma unroll
    for (int cf = 0; cf < 4; ++cf) {
      const u16* va = vtc + (cf * 16 + l16) * 72 + quad * 8;
      v0f[cf] = *(const short8*)(va);
      v1f[cf] = *(const short8*)(va + 32);
    }

    // exp2 + partial sums + in-register pack (P stays in VGPRs)
    uint2 pp[4];
    #pragma unroll
    for (int jt = 0; jt < 4; ++jt) {
      const float e0 = __builtin_amdgcn_exp2f(S[jt][0]);
      const float e1 = __builtin_amdgcn_exp2f(S[jt][1]);
      const float e2 = __builtin_amdgcn_exp2f(S[jt][2]);
      const float e3 = __builtin_amdgcn_exp2f(S[jt][3]);
      lsA += e0 + e1;
      lsB += e2 + e3;
      pp[jt].x = pk2t(e0, e1);
      pp[jt].y = pk2t(e2, e3);
    }

    // O += P * V : A = P (in regs, j-order restored by sigma), B = v[c][j]
    __builtin_amdgcn_s_setprio(1);
    {
      const short8 pa0 = mk8(pp[0].x, pp[0].y, pp[1].x, pp[1].y);
      const short8 pa1 = mk8(pp[2].x, pp[2].y, pp[3].x, pp[3].y);
      #pragma unroll
      for (int cf = 0; cf < 4; ++cf) {
        O[cf] = __builtin_amdgcn_mfma_f32_16x16x32_bf16(pa0, v0f[cf], O[cf], 0, 0, 0);
        O[cf] = __builtin_amdgcn_mfma_f32_16x16x32_bf16(pa1, v1f[cf], O[cf], 0, 0, 0);
      }
    }
    __builtin_amdgcn_s_setprio(0);

    if (it < 15) {
      u16* ktn = smem + ((it + 1) & 1) * 9216;
      *(uint4*)(ktn + sr * 72 + c_st)              = rk0;
      *(uint4*)(ktn + sr * 72 + c_st + 8)          = rk1;
      *(uint4*)(ktn + 4608 + r_st * 72 + c_st)     = rv0;
      *(uint4*)(ktn + 4608 + r_st * 72 + c_st + 8) = rv1;
    }
    __syncthreads();
  }

  float lsum = lsA + lsB;
  lsum += __shfl_xor(lsum, 16, 64);
  lsum += __shfl_xor(lsum, 32, 64);

  __syncthreads();   // reuse LDS for epilogue transpose
  float* of = (float*)smem + wave * 1280;   // [64 c][20] per wave
  #pragma unroll
  for (int r = 0; r < 4; ++r) {
    const float rl = __builtin_amdgcn_rcpf(__shfl(lsum, quad * 4 + r, 64));
    #pragma unroll
    for (int cf = 0; cf < 4; ++cf)
      O[cf][r] *= rl;
  }
  asm volatile("" ::: "memory");
  #pragma unroll
  for (int cf = 0; cf < 4; ++cf)
    #pragma unroll
    for (int r = 0; r < 4; ++r)
      of[(cf * 16 + l16) * 20 + quad * 4 + r] = O[cf][r];
  asm volatile("" ::: "memory");
  {
    float* ob = out + ((size_t)bt * CC) * LL + i0w;
    #pragma unroll
    for (int rr = 0; rr < 4; ++rr) {
      const int c = rr * 16 + l16;
      float4 val = *(const float4*)(of + c * 20 + quad * 4);
      *(float4*)(ob + (size_t)c * LL + quad * 4) = val;
    }
  }
  asm volatile("" ::: "memory");
}

extern "C" void kernel_launch(void* const* d_in, const int* in_sizes, int n_in,
                              void* d_out, int out_size, void* d_ws, size_t ws_size,
                              hipStream_t stream) {
  const float* x  = (const float*)d_in[0];
  const float* Wq = (const float*)d_in[1];
  const float* bq = (const float*)d_in[2];
  const float* Wk = (const float*)d_in[3];
  const float* bk = (const float*)d_in[4];
  const float* Wv = (const float*)d_in[5];
  const float* bv = (const float*)d_in[6];
  float* out = (float*)d_out;

  u16* qTp = (u16*)d_ws;                          // 8 MB
  u16* kTp = qTp + (size_t)64 * LL * CC;          // 8 MB
  u16* vp  = kTp + (size_t)64 * LL * CC;          // 8 MB

  qkv_kernel<<<512, 256, 0, stream>>>(x, Wq, bq, Wk, bk, Wv, bv, qTp, kTp, vp);
  attn_kernel<<<1024, 256, 0, stream>>>(qTp, kTp, vp, out);
}